// Round 12
// baseline (634.115 us; speedup 1.0000x reference)
//
#include <hip/hip_runtime.h>
#include <cstdint>

namespace {

constexpr int ROWS = 256;            // B*C
constexpr int ROW_N = 65536;         // H*W
constexpr int ST = 1024;             // threads per sort block (16 waves)
constexpr int CHUNK = 2048;          // elements per block-wide chunk
constexpr int NCHUNK = ROW_N / CHUNK;  // 32
constexpr int SUBS = 32;             // 2 slots x 16 waves (position-ordered)
constexpr int EPT = 2;               // elements per thread per chunk
constexpr size_t NTOT = (size_t)ROWS * ROW_N;

constexpr float COS_02PI = 0.80901699437494745f;  // cos(0.2*pi)
constexpr float COS_04PI = 0.30901699437494745f;  // cos(0.4*pi)

typedef float f4v __attribute__((ext_vector_type(4)));

struct SortSmem {
    __align__(16) uint32_t whist[SUBS * 256];  // 32 KB u32 (LDS-atomic counters)
    __align__(16) uint32_t stage[CHUNK];       // 8 KB digit-ordered stage
    __align__(16) uint8_t  dstg[CHUNK];        // 2 KB digit-per-slot (src P0 only)
    __align__(16) uint32_t hist[256];          // next-pass histogram
    uint32_t sbase[2][256];                    // running global digit base (ping-pong)
    uint32_t adj[2][256];                      // sbase - lstart, per parity
    uint32_t wavesum[4];
};  // ~47 KB -> 2 blocks/CU

__device__ __forceinline__ uint32_t fkey(float x) {
    return __float_as_uint(fabsf(x));  // monotone for non-negative floats
}

__device__ void prepass_hist(SortSmem& sm, const float* __restrict__ rawA)
{
    // pass-0 digit histogram: digit = (fkey>>10)&255 (mantissa bits, ~uniform)
    const int tid = threadIdx.x;
    const float4* r4 = (const float4*)rawA;
#pragma unroll 4
    for (int i = 0; i < ROW_N / 4 / ST; ++i) {   // 16
        float4 f = r4[i * ST + tid];
        atomicAdd(&sm.hist[(fkey(f.x) >> 10) & 255u], 1u);
        atomicAdd(&sm.hist[(fkey(f.y) >> 10) & 255u], 1u);
        atomicAdd(&sm.hist[(fkey(f.z) >> 10) & 255u], 1u);
        atomicAdd(&sm.hist[(fkey(f.w) >> 10) & 255u], 1u);
    }
    __syncthreads();
}

// One stable radix pass. Key = bits [31:10] of |x| (22 bits, bit31 always 0).
// Digit plan: P0 bits 10-17 (8b), P1 bits 18-24 (7b), P2 bits 25-31 (7b).
// ALL buffers u32. src element after P0: fkey[31:18]<<18 | sneg<<17 | cneg<<16 | idx16.
// tgt element: full |x| bits throughout.
// Rank via ds_atomic_add_rtn on wave-private (sub,digit) counters — replaces
// the ballot-mask rank machinery (~40 VALU/elem) with 1 LDS atomic + ~4 VALU.
// Stability: sub = k*16+wave is position-monotone; within a sub, same-address
// LDS atomics of one wave instruction retire in lane order; e[0]'s atomic
// precedes e[1]'s in program order.
template <bool IS_SRC, int P>
__device__ void run_pass(SortSmem& sm, const float* __restrict__ rawA,
                         const float* __restrict__ rawS,
                         const uint32_t* __restrict__ inBuf,
                         uint32_t* __restrict__ outBuf)
{
    constexpr int DBITS = (P == 0) ? 8 : 7;
    constexpr int ND = 1 << DBITS;
    constexpr int DSH = (P == 0) ? 10 : (P == 1 ? 18 : 25);  // digit shift in staged val
    constexpr bool P0SRC = IS_SRC && (P == 0);

    const int tid = threadIdx.x;
    const int lane = tid & 63;
    const int wave = tid >> 6;
    const uint64_t lane_lt = (1ull << lane) - 1ull;

    // ---- pass start: sbase[0] = exclusive scan of hist; zero hist for reuse ----
    {
        uint32_t h = 0u, incl = 0u;
        if (tid < ND) {
            h = sm.hist[tid];
            sm.hist[tid] = 0u;
            incl = h;
#pragma unroll
            for (int dd = 1; dd < 64; dd <<= 1) {
                uint32_t t = __shfl_up(incl, dd, 64);
                if (lane >= dd) incl += t;
            }
            if (lane == 63) sm.wavesum[tid >> 6] = incl;
        }
        __syncthreads();
        if (tid < ND) {
            uint32_t woff = 0u;
#pragma unroll
            for (int j = 0; j < ND / 64; ++j)
                if (j < (tid >> 6)) woff += sm.wavesum[j];
            sm.sbase[0][tid] = woff + incl - h;
        }
        __syncthreads();
    }

    // returns {value, digit}
    auto loadE = [&](int c, int k) -> uint2 {
        const int pos = c * CHUNK + (k << 10) + (wave << 6) + lane;
        if constexpr (P == 0) {
            float av = rawA[pos];
            uint32_t kk = fkey(av);
            if constexpr (IS_SRC) {
                float sv = rawS[pos];
                uint32_t o = ((kk >> 18) << 18) | (uint32_t)pos;
                if (av < 0.f) o |= 1u << 16;
                if (sv < 0.f) o |= 1u << 17;
                return make_uint2(o, (kk >> 10) & 255u);
            } else {
                return make_uint2(kk, (kk >> 10) & 255u);
            }
        } else {
            uint32_t v = inBuf[pos];
            return make_uint2(v, (v >> DSH) & (ND - 1));
        }
    };

    uint2 e[EPT];
#pragma unroll
    for (int k = 0; k < EPT; ++k) e[k] = loadE(0, k);

    for (int c = 0; c < NCHUNK; ++c) {
        const int par = c & 1;

        // ---- zero own whist rows (wave-private, program-ordered vs own atomics) ----
        {
            uint4 z = make_uint4(0u, 0u, 0u, 0u);
#pragma unroll
            for (int k = 0; k < EPT; ++k) {
                uint4* rp = (uint4*)&sm.whist[(k * 16 + wave) * ND];
                if (lane < ND / 4) rp[lane] = z;
            }
        }

        // ---- rank via LDS atomic-return (1 op/elem; e[0] before e[1]) ----
        uint32_t rk[EPT];
#pragma unroll
        for (int k = 0; k < EPT; ++k)
            rk[k] = atomicAdd(&sm.whist[(k * 16 + wave) * ND + e[k].y], 1u);

        // ---- fused histogram for next pass ----
        if constexpr (P == 0) {
            // next digit = bits 18-24 (mostly mantissa): plain atomics
#pragma unroll
            for (int k = 0; k < EPT; ++k)
                atomicAdd(&sm.hist[(e[k].x >> 18) & 127u], 1u);
        } else if constexpr (P == 1) {
            // next digit = exponent bits 25-31: skewed -> leader-aggregated
#pragma unroll
            for (int k = 0; k < EPT; ++k) {
                const uint32_t nd = (e[k].x >> 25) & 127u;
                uint64_t m = ~0ull;
#pragma unroll
                for (int b = 0; b < 7; ++b) {
                    uint64_t bal = __ballot((nd >> b) & 1u);
                    m &= ((nd >> b) & 1u) ? bal : ~bal;
                }
                if ((m & lane_lt) == 0ull)
                    atomicAdd(&sm.hist[nd], (uint32_t)__popcll(m));
            }
        }
        __syncthreads();  // b1: whist counts complete

        // ---- scan A: per-digit totals + wave-level inclusive scan ----
        uint32_t tot = 0u, incl = 0u;
        if (tid < ND) {
#pragma unroll
            for (int s = 0; s < SUBS; ++s) tot += sm.whist[s * ND + tid];
            incl = tot;
#pragma unroll
            for (int dd = 1; dd < 64; dd <<= 1) {
                uint32_t t = __shfl_up(incl, dd, 64);
                if (lane >= dd) incl += t;
            }
            if (lane == 63) sm.wavesum[tid >> 6] = incl;
        }
        __syncthreads();  // b1b

        // ---- scan B: local starts -> whist local prefixes; adj & next sbase ----
        if (tid < ND) {
            uint32_t woff = 0u;
#pragma unroll
            for (int j = 0; j < ND / 64; ++j)
                if (j < (tid >> 6)) woff += sm.wavesum[j];
            const uint32_t ls = woff + incl - tot;
            uint32_t run = ls;
#pragma unroll
            for (int s = 0; s < SUBS; ++s) {
                uint32_t t = sm.whist[s * ND + tid];
                sm.whist[s * ND + tid] = run;
                run += t;
            }
            const uint32_t sb = sm.sbase[par][tid];
            sm.adj[par][tid] = sb - ls;
            sm.sbase[par ^ 1][tid] = sb + tot;
        }
        __syncthreads();  // b2: local offsets ready

        // ---- LDS stage scatter (slot = base + rank) + global prefetch ----
#pragma unroll
        for (int k = 0; k < EPT; ++k) {
            const uint32_t s = sm.whist[(k * 16 + wave) * ND + e[k].y] + rk[k];
            sm.stage[s] = e[k].x;
            if constexpr (P0SRC) sm.dstg[s] = (uint8_t)e[k].y;
        }
        uint2 n[EPT];
#pragma unroll
        for (int k = 0; k < EPT; ++k) n[k] = make_uint2(0u, 0u);
        if (c + 1 < NCHUNK) {
#pragma unroll
            for (int k = 0; k < EPT; ++k) n[k] = loadE(c + 1, k);
        }
        __syncthreads();  // b3: stage complete

        // ---- coalesced copy-out: slot i -> adj[d] + i ----
#pragma unroll
        for (int h = 0; h < EPT; ++h) {
            const int slot = tid + (h << 10);
            const uint32_t u = sm.stage[slot];
            uint32_t d;
            if constexpr (P0SRC) d = sm.dstg[slot];
            else                 d = (u >> DSH) & (ND - 1);
            const uint32_t go = sm.adj[par][d] + (uint32_t)slot;
            uint32_t ov = u;
            if constexpr (IS_SRC && P == 2) ov = u & 0x3FFFFu;  // idx+signs only
            outBuf[go] = ov;
        }
#pragma unroll
        for (int k = 0; k < EPT; ++k) e[k] = n[k];
    }
    __syncthreads();  // seal pass: writes drained before next pass reads
}

__device__ __forceinline__ float detail_one(float c, float s) {
    const float f = (c < 0.f) ? ((s < 0.f) ? -1.f : COS_04PI)
                              : ((s < 0.f) ? -COS_04PI : 1.f);
    return (0.4f * fabsf(c) + 0.6f * fabsf(s)) * f;
}

} // namespace

__global__ __launch_bounds__(ST, 8)
void sort_kernel(const float* __restrict__ ca, const float* __restrict__ sa,
                 uint32_t* srcA, uint32_t* srcB,
                 uint32_t* tgtA, uint32_t* tgtB, uint32_t* tgtF)
{
    __shared__ SortSmem sm;
    const int row = blockIdx.x >> 1;
    if (threadIdx.x < 256) sm.hist[threadIdx.x] = 0u;
    __syncthreads();

    if ((blockIdx.x & 1) == 0) {
        const float* cRow = ca + (size_t)row * ROW_N;
        const float* sRow = sa + (size_t)row * ROW_N;
        uint32_t* A = srcA + (size_t)row * ROW_N;
        uint32_t* B = srcB + (size_t)row * ROW_N;
        prepass_hist(sm, cRow);
        run_pass<true, 0>(sm, cRow, sRow, nullptr, A);
        run_pass<true, 1>(sm, nullptr, nullptr, A, B);
        run_pass<true, 2>(sm, nullptr, nullptr, B, A);  // final: back into A (srcF)
    } else {
        const float* sRow = sa + (size_t)row * ROW_N;
        uint32_t* A = tgtA + (size_t)row * ROW_N;
        uint32_t* B = tgtB + (size_t)row * ROW_N;
        uint32_t* F = tgtF + (size_t)row * ROW_N;
        prepass_hist(sm, sRow);
        run_pass<false, 0>(sm, sRow, nullptr, nullptr, A);
        run_pass<false, 1>(sm, nullptr, nullptr, A, B);
        run_pass<false, 2>(sm, nullptr, nullptr, B, F);
    }
}

// out0[row, idx] = t_sorted[row, k] * cos(0.8*ph(c) + 0.2*ph(s))
// srcF flat u32 [ROWS][ROW_N]: idx16 | cneg<<16 | sneg<<17 (rank order).
// tgtF flat u32 [ROWS][ROW_N]: exact |style| float bits, sorted.
__global__ __launch_bounds__(256)
void approx_finalize(const uint32_t* __restrict__ srcF,
                     const uint32_t* __restrict__ tgtF,
                     float* __restrict__ out0)
{
    const size_t kk = (size_t)blockIdx.x * blockDim.x + threadIdx.x;
    const uint32_t v = srcF[kk];
    const size_t j = ((kk >> 16) << 16) | (v & 0xFFFFu);
    const float t = __uint_as_float(tgtF[kk]);
    const uint32_t cneg = (v >> 16) & 1u;
    const uint32_t sneg = (v >> 17) & 1u;
    const float f = cneg ? (sneg ? -1.f : -COS_02PI)
                         : (sneg ? COS_02PI : 1.f);
    out0[j] = t * f;
}

__global__ __launch_bounds__(256)
void details_kernel(const f4v* __restrict__ ch, const f4v* __restrict__ sh,
                    const f4v* __restrict__ cv, const f4v* __restrict__ sv,
                    const f4v* __restrict__ cd, const f4v* __restrict__ sd,
                    f4v* __restrict__ oh, f4v* __restrict__ ov,
                    f4v* __restrict__ od)
{
    const size_t i = (size_t)blockIdx.x * blockDim.x + threadIdx.x;
    f4v a, b, r;
    a = ch[i]; b = sh[i];
    r.x = detail_one(a.x, b.x); r.y = detail_one(a.y, b.y);
    r.z = detail_one(a.z, b.z); r.w = detail_one(a.w, b.w);
    oh[i] = r;
    a = cv[i]; b = sv[i];
    r.x = detail_one(a.x, b.x); r.y = detail_one(a.y, b.y);
    r.z = detail_one(a.z, b.z); r.w = detail_one(a.w, b.w);
    ov[i] = r;
    a = cd[i]; b = sd[i];
    r.x = detail_one(a.x, b.x); r.y = detail_one(a.y, b.y);
    r.z = detail_one(a.z, b.z); r.w = detail_one(a.w, b.w);
    od[i] = r;
}

extern "C" void kernel_launch(void* const* d_in, const int* in_sizes, int n_in,
                              void* d_out, int out_size, void* d_ws, size_t ws_size,
                              hipStream_t stream)
{
    (void)in_sizes; (void)n_in; (void)out_size; (void)ws_size;
    const float* ca = (const float*)d_in[0];
    const float* ch = (const float*)d_in[1];
    const float* cv = (const float*)d_in[2];
    const float* cd = (const float*)d_in[3];
    const float* sa = (const float*)d_in[4];
    const float* sh = (const float*)d_in[5];
    const float* sv = (const float*)d_in[6];
    const float* sd = (const float*)d_in[7];

    float* out = (float*)d_out;
    float* out_a = out;
    float* out_h = out + NTOT;
    float* out_v = out + 2 * NTOT;
    float* out_d = out + 3 * NTOT;

    // Buffers (all u32; ws >= 192 MiB used, >=256 MiB proven by R10):
    //  src: P0 raw -> srcA (ws[0,64MiB)); P1 srcA -> srcB (ws[64,128));
    //       P2 srcB -> srcA (= srcF, flat idx+signs in rank order).
    //  tgt: P0 -> out_d slice; P1 -> out_h slice; P2 -> tgtF (ws[128,192)).
    //  finalize reads ONLY ws (srcF + tgtF) -> out_h/v/d free for details.
    //  Keep sort scatter isolated from streaming traffic (R8/R10 lesson).
    uint32_t* srcA = (uint32_t*)d_ws;
    uint32_t* srcB = (uint32_t*)((char*)d_ws + NTOT * 4);
    uint32_t* tgtF = (uint32_t*)((char*)d_ws + NTOT * 8);
    uint32_t* tgtA = (uint32_t*)out_d;
    uint32_t* tgtB = (uint32_t*)out_h;

    sort_kernel<<<2 * ROWS, ST, 0, stream>>>(ca, sa, srcA, srcB, tgtA, tgtB, tgtF);

    approx_finalize<<<(int)(NTOT / 256), 256, 0, stream>>>(srcA, tgtF, out_a);

    details_kernel<<<(int)(NTOT / 4 / 256), 256, 0, stream>>>(
        (const f4v*)ch, (const f4v*)sh,
        (const f4v*)cv, (const f4v*)sv,
        (const f4v*)cd, (const f4v*)sd,
        (f4v*)out_h, (f4v*)out_v, (f4v*)out_d);
}

// Round 13
// 551.627 us; speedup vs baseline: 1.1495x; 1.1495x over previous
//
#include <hip/hip_runtime.h>
#include <cstdint>

namespace {

constexpr int ROWS = 256;            // B*C
constexpr int ROW_N = 65536;         // H*W
constexpr int ST = 1024;             // threads per sort block (16 waves)
constexpr int CHUNK = 4096;          // elements per block-wide chunk
constexpr int NCHUNK = ROW_N / CHUNK;  // 16
constexpr int SUBS = 16;             // sub = wave (contiguous 256-elem segment)
constexpr int EPT = 4;               // elements per thread per chunk
constexpr size_t NTOT = (size_t)ROWS * ROW_N;

constexpr float COS_02PI = 0.80901699437494745f;  // cos(0.2*pi)
constexpr float COS_04PI = 0.30901699437494745f;  // cos(0.4*pi)

typedef float f4v __attribute__((ext_vector_type(4)));

struct SortSmem {
    __align__(16) uint32_t whist[SUBS * 256];  // 16 KB u32 (LDS-atomic counters)
    __align__(16) uint32_t stage[CHUNK];       // 16 KB digit-ordered stage
    __align__(16) uint8_t  dstg[CHUNK];        // 4 KB digit-per-slot (src P0 only)
    __align__(16) uint32_t hist[256];          // next-pass histogram
    uint32_t sbase[2][256];                    // running global digit base (ping-pong)
    uint32_t adj[2][256];                      // sbase - lstart, per parity
    uint32_t wavesum[4];
};  // ~42 KB -> 2 blocks/CU

__device__ __forceinline__ uint32_t fkey(float x) {
    return __float_as_uint(fabsf(x));  // monotone for non-negative floats
}

__device__ void prepass_hist(SortSmem& sm, const float* __restrict__ rawA)
{
    // pass-0 digit histogram: digit = (fkey>>10)&255 (mantissa bits, ~uniform)
    const int tid = threadIdx.x;
    const float4* r4 = (const float4*)rawA;
#pragma unroll 4
    for (int i = 0; i < ROW_N / 4 / ST; ++i) {   // 16
        float4 f = r4[i * ST + tid];
        atomicAdd(&sm.hist[(fkey(f.x) >> 10) & 255u], 1u);
        atomicAdd(&sm.hist[(fkey(f.y) >> 10) & 255u], 1u);
        atomicAdd(&sm.hist[(fkey(f.z) >> 10) & 255u], 1u);
        atomicAdd(&sm.hist[(fkey(f.w) >> 10) & 255u], 1u);
    }
    __syncthreads();
}

// One stable radix pass. Key = bits [31:10] of |x| (22 bits, bit31 always 0).
// Digit plan: P0 bits 10-17 (8b), P1 bits 18-24 (7b), P2 bits 25-31 (7b).
// ALL buffers u32. src element after P0: fkey[31:18]<<18 | sneg<<17 | cneg<<16 | idx16.
// tgt element: full |x| bits throughout.
// Rank via ds_atomic_add_rtn on wave-private digit counters (sub = wave).
// Position map: pos = c*4096 + wave*256 + k*64 + lane — each wave owns a
// contiguous 256-elem segment, so (program-order k) x (lane-order retirement)
// = position order within the sub [validated R12: absmax unchanged], and
// sub index (wave) is position-monotone across subs.
template <bool IS_SRC, int P>
__device__ void run_pass(SortSmem& sm, const float* __restrict__ rawA,
                         const float* __restrict__ rawS,
                         const uint32_t* __restrict__ inBuf,
                         uint32_t* __restrict__ outBuf)
{
    constexpr int DBITS = (P == 0) ? 8 : 7;
    constexpr int ND = 1 << DBITS;
    constexpr int DSH = (P == 0) ? 10 : (P == 1 ? 18 : 25);  // digit shift in staged val
    constexpr bool P0SRC = IS_SRC && (P == 0);

    const int tid = threadIdx.x;
    const int lane = tid & 63;
    const int wave = tid >> 6;
    const uint64_t lane_lt = (1ull << lane) - 1ull;

    // ---- pass start: sbase[0] = exclusive scan of hist; zero hist for reuse ----
    {
        uint32_t h = 0u, incl = 0u;
        if (tid < ND) {
            h = sm.hist[tid];
            sm.hist[tid] = 0u;
            incl = h;
#pragma unroll
            for (int dd = 1; dd < 64; dd <<= 1) {
                uint32_t t = __shfl_up(incl, dd, 64);
                if (lane >= dd) incl += t;
            }
            if (lane == 63) sm.wavesum[tid >> 6] = incl;
        }
        __syncthreads();
        if (tid < ND) {
            uint32_t woff = 0u;
#pragma unroll
            for (int j = 0; j < ND / 64; ++j)
                if (j < (tid >> 6)) woff += sm.wavesum[j];
            sm.sbase[0][tid] = woff + incl - h;
        }
        __syncthreads();
    }

    // returns {value, digit}; pos = c*CHUNK + wave*256 + k*64 + lane
    auto loadE = [&](int c, int k) -> uint2 {
        const int pos = c * CHUNK + (wave << 8) + (k << 6) + lane;
        if constexpr (P == 0) {
            float av = rawA[pos];
            uint32_t kk = fkey(av);
            if constexpr (IS_SRC) {
                float sv = rawS[pos];
                uint32_t o = ((kk >> 18) << 18) | (uint32_t)pos;
                if (av < 0.f) o |= 1u << 16;
                if (sv < 0.f) o |= 1u << 17;
                return make_uint2(o, (kk >> 10) & 255u);
            } else {
                return make_uint2(kk, (kk >> 10) & 255u);
            }
        } else {
            uint32_t v = inBuf[pos];
            return make_uint2(v, (v >> DSH) & (ND - 1));
        }
    };

    uint2 e[EPT];
#pragma unroll
    for (int k = 0; k < EPT; ++k) e[k] = loadE(0, k);

    for (int c = 0; c < NCHUNK; ++c) {
        const int par = c & 1;

        // ---- zero own whist row (wave-private, program-ordered vs own atomics) ----
        {
            uint4 z = make_uint4(0u, 0u, 0u, 0u);
            uint4* rp = (uint4*)&sm.whist[wave * ND];
            if (lane < ND / 4) rp[lane] = z;
        }

        // ---- rank via LDS atomic-return (k=0..3 in program order) ----
        uint32_t rk[EPT];
#pragma unroll
        for (int k = 0; k < EPT; ++k)
            rk[k] = atomicAdd(&sm.whist[(wave << DBITS) + e[k].y], 1u);

        // ---- fused histogram for next pass ----
        if constexpr (P == 0) {
            // next digit = bits 18-24 (mostly mantissa): plain atomics
#pragma unroll
            for (int k = 0; k < EPT; ++k)
                atomicAdd(&sm.hist[(e[k].x >> 18) & 127u], 1u);
        } else if constexpr (P == 1) {
            // next digit = exponent bits 25-31: skewed -> leader-aggregated
#pragma unroll
            for (int k = 0; k < EPT; ++k) {
                const uint32_t nd = (e[k].x >> 25) & 127u;
                uint64_t m = ~0ull;
#pragma unroll
                for (int b = 0; b < 7; ++b) {
                    uint64_t bal = __ballot((nd >> b) & 1u);
                    m &= ((nd >> b) & 1u) ? bal : ~bal;
                }
                if ((m & lane_lt) == 0ull)
                    atomicAdd(&sm.hist[nd], (uint32_t)__popcll(m));
            }
        }
        __syncthreads();  // b1: whist counts complete

        // ---- scan A: per-digit totals + wave-level inclusive scan ----
        uint32_t tot = 0u, incl = 0u;
        if (tid < ND) {
#pragma unroll
            for (int s = 0; s < SUBS; ++s) tot += sm.whist[(s << DBITS) + tid];
            incl = tot;
#pragma unroll
            for (int dd = 1; dd < 64; dd <<= 1) {
                uint32_t t = __shfl_up(incl, dd, 64);
                if (lane >= dd) incl += t;
            }
            if (lane == 63) sm.wavesum[tid >> 6] = incl;
        }
        __syncthreads();  // b1b

        // ---- scan B: local starts -> whist local prefixes; adj & next sbase ----
        if (tid < ND) {
            uint32_t woff = 0u;
#pragma unroll
            for (int j = 0; j < ND / 64; ++j)
                if (j < (tid >> 6)) woff += sm.wavesum[j];
            const uint32_t ls = woff + incl - tot;
            uint32_t run = ls;
#pragma unroll
            for (int s = 0; s < SUBS; ++s) {
                uint32_t t = sm.whist[(s << DBITS) + tid];
                sm.whist[(s << DBITS) + tid] = run;
                run += t;
            }
            const uint32_t sb = sm.sbase[par][tid];
            sm.adj[par][tid] = sb - ls;
            sm.sbase[par ^ 1][tid] = sb + tot;
        }
        __syncthreads();  // b2: local offsets ready

        // ---- LDS stage scatter (slot = base + rank) + global prefetch ----
#pragma unroll
        for (int k = 0; k < EPT; ++k) {
            const uint32_t s = sm.whist[(wave << DBITS) + e[k].y] + rk[k];
            sm.stage[s] = e[k].x;
            if constexpr (P0SRC) sm.dstg[s] = (uint8_t)e[k].y;
        }
        uint2 n[EPT];
#pragma unroll
        for (int k = 0; k < EPT; ++k) n[k] = make_uint2(0u, 0u);
        if (c + 1 < NCHUNK) {
#pragma unroll
            for (int k = 0; k < EPT; ++k) n[k] = loadE(c + 1, k);
        }
        __syncthreads();  // b3: stage complete

        // ---- coalesced copy-out: slot i -> adj[d] + i ----
#pragma unroll
        for (int h = 0; h < EPT; ++h) {
            const int slot = tid + (h << 10);
            const uint32_t u = sm.stage[slot];
            uint32_t d;
            if constexpr (P0SRC) d = sm.dstg[slot];
            else                 d = (u >> DSH) & (ND - 1);
            const uint32_t go = sm.adj[par][d] + (uint32_t)slot;
            uint32_t ov = u;
            if constexpr (IS_SRC && P == 2) ov = u & 0x3FFFFu;  // idx+signs only
            outBuf[go] = ov;
        }
#pragma unroll
        for (int k = 0; k < EPT; ++k) e[k] = n[k];
    }
    __syncthreads();  // seal pass: writes drained before next pass reads
}

__device__ __forceinline__ float detail_one(float c, float s) {
    const float f = (c < 0.f) ? ((s < 0.f) ? -1.f : COS_04PI)
                              : ((s < 0.f) ? -COS_04PI : 1.f);
    return (0.4f * fabsf(c) + 0.6f * fabsf(s)) * f;
}

} // namespace

__global__ __launch_bounds__(ST, 8)
void sort_kernel(const float* __restrict__ ca, const float* __restrict__ sa,
                 uint32_t* srcA, uint32_t* srcB,
                 uint32_t* tgtA, uint32_t* tgtB, uint32_t* tgtF)
{
    __shared__ SortSmem sm;
    const int row = blockIdx.x >> 1;
    if (threadIdx.x < 256) sm.hist[threadIdx.x] = 0u;
    __syncthreads();

    if ((blockIdx.x & 1) == 0) {
        const float* cRow = ca + (size_t)row * ROW_N;
        const float* sRow = sa + (size_t)row * ROW_N;
        uint32_t* A = srcA + (size_t)row * ROW_N;
        uint32_t* B = srcB + (size_t)row * ROW_N;
        prepass_hist(sm, cRow);
        run_pass<true, 0>(sm, cRow, sRow, nullptr, A);
        run_pass<true, 1>(sm, nullptr, nullptr, A, B);
        run_pass<true, 2>(sm, nullptr, nullptr, B, A);  // final: back into A (srcF)
    } else {
        const float* sRow = sa + (size_t)row * ROW_N;
        uint32_t* A = tgtA + (size_t)row * ROW_N;
        uint32_t* B = tgtB + (size_t)row * ROW_N;
        uint32_t* F = tgtF + (size_t)row * ROW_N;
        prepass_hist(sm, sRow);
        run_pass<false, 0>(sm, sRow, nullptr, nullptr, A);
        run_pass<false, 1>(sm, nullptr, nullptr, A, B);
        run_pass<false, 2>(sm, nullptr, nullptr, B, F);
    }
}

// out0[row, idx] = t_sorted[row, k] * cos(0.8*ph(c) + 0.2*ph(s))
// srcF flat u32 [ROWS][ROW_N]: idx16 | cneg<<16 | sneg<<17 (rank order).
// tgtF flat u32 [ROWS][ROW_N]: exact |style| float bits, sorted.
__global__ __launch_bounds__(256)
void approx_finalize(const uint32_t* __restrict__ srcF,
                     const uint32_t* __restrict__ tgtF,
                     float* __restrict__ out0)
{
    const size_t kk = (size_t)blockIdx.x * blockDim.x + threadIdx.x;
    const uint32_t v = srcF[kk];
    const size_t j = ((kk >> 16) << 16) | (v & 0xFFFFu);
    const float t = __uint_as_float(tgtF[kk]);
    const uint32_t cneg = (v >> 16) & 1u;
    const uint32_t sneg = (v >> 17) & 1u;
    const float f = cneg ? (sneg ? -1.f : -COS_02PI)
                         : (sneg ? COS_02PI : 1.f);
    out0[j] = t * f;
}

__global__ __launch_bounds__(256)
void details_kernel(const f4v* __restrict__ ch, const f4v* __restrict__ sh,
                    const f4v* __restrict__ cv, const f4v* __restrict__ sv,
                    const f4v* __restrict__ cd, const f4v* __restrict__ sd,
                    f4v* __restrict__ oh, f4v* __restrict__ ov,
                    f4v* __restrict__ od)
{
    const size_t i = (size_t)blockIdx.x * blockDim.x + threadIdx.x;
    f4v a, b, r;
    a = ch[i]; b = sh[i];
    r.x = detail_one(a.x, b.x); r.y = detail_one(a.y, b.y);
    r.z = detail_one(a.z, b.z); r.w = detail_one(a.w, b.w);
    oh[i] = r;
    a = cv[i]; b = sv[i];
    r.x = detail_one(a.x, b.x); r.y = detail_one(a.y, b.y);
    r.z = detail_one(a.z, b.z); r.w = detail_one(a.w, b.w);
    ov[i] = r;
    a = cd[i]; b = sd[i];
    r.x = detail_one(a.x, b.x); r.y = detail_one(a.y, b.y);
    r.z = detail_one(a.z, b.z); r.w = detail_one(a.w, b.w);
    od[i] = r;
}

extern "C" void kernel_launch(void* const* d_in, const int* in_sizes, int n_in,
                              void* d_out, int out_size, void* d_ws, size_t ws_size,
                              hipStream_t stream)
{
    (void)in_sizes; (void)n_in; (void)out_size; (void)ws_size;
    const float* ca = (const float*)d_in[0];
    const float* ch = (const float*)d_in[1];
    const float* cv = (const float*)d_in[2];
    const float* cd = (const float*)d_in[3];
    const float* sa = (const float*)d_in[4];
    const float* sh = (const float*)d_in[5];
    const float* sv = (const float*)d_in[6];
    const float* sd = (const float*)d_in[7];

    float* out = (float*)d_out;
    float* out_a = out;
    float* out_h = out + NTOT;
    float* out_v = out + 2 * NTOT;
    float* out_d = out + 3 * NTOT;

    // Buffers (all u32; ws >= 192 MiB used, >=256 MiB proven by R10):
    //  src: P0 raw -> srcA (ws[0,64MiB)); P1 srcA -> srcB (ws[64,128));
    //       P2 srcB -> srcA (= srcF, flat idx+signs in rank order).
    //  tgt: P0 -> out_d slice; P1 -> out_h slice; P2 -> tgtF (ws[128,192)).
    //  finalize reads ONLY ws (srcF + tgtF) -> out_h/v/d free for details.
    //  Keep sort scatter isolated from streaming traffic (R8/R10 lesson).
    uint32_t* srcA = (uint32_t*)d_ws;
    uint32_t* srcB = (uint32_t*)((char*)d_ws + NTOT * 4);
    uint32_t* tgtF = (uint32_t*)((char*)d_ws + NTOT * 8);
    uint32_t* tgtA = (uint32_t*)out_d;
    uint32_t* tgtB = (uint32_t*)out_h;

    sort_kernel<<<2 * ROWS, ST, 0, stream>>>(ca, sa, srcA, srcB, tgtA, tgtB, tgtF);

    approx_finalize<<<(int)(NTOT / 256), 256, 0, stream>>>(srcA, tgtF, out_a);

    details_kernel<<<(int)(NTOT / 4 / 256), 256, 0, stream>>>(
        (const f4v*)ch, (const f4v*)sh,
        (const f4v*)cv, (const f4v*)sv,
        (const f4v*)cd, (const f4v*)sd,
        (f4v*)out_h, (f4v*)out_v, (f4v*)out_d);
}

// Round 14
// 516.436 us; speedup vs baseline: 1.2279x; 1.0681x over previous
//
#include <hip/hip_runtime.h>
#include <cstdint>

namespace {

constexpr int ROWS = 256;            // B*C
constexpr int ROW_N = 65536;         // H*W
constexpr int ST = 1024;             // threads per sort block (16 waves)
constexpr int CHUNK = 8192;          // elements per block-wide chunk
constexpr int NCHUNK = ROW_N / CHUNK;  // 8
constexpr int SUBS = 16;             // sub = wave (contiguous 512-elem segment)
constexpr int EPT = 8;               // elements per thread per chunk
constexpr size_t NTOT = (size_t)ROWS * ROW_N;

constexpr float COS_02PI = 0.80901699437494745f;  // cos(0.2*pi)
constexpr float COS_04PI = 0.30901699437494745f;  // cos(0.4*pi)

typedef float f4v __attribute__((ext_vector_type(4)));

struct SortSmem {
    __align__(16) uint32_t whist[SUBS * 256];  // 16 KB u32 (LDS-atomic counters)
    __align__(16) uint32_t stage[CHUNK];       // 32 KB digit-ordered stage
    __align__(16) uint8_t  dstg[CHUNK];        // 8 KB digit-per-slot (src P0 only)
    __align__(16) uint32_t hist[256];          // next-pass histogram
    uint32_t sbase[2][256];                    // running global digit base (ping-pong)
    uint32_t adj[2][256];                      // sbase - lstart, per parity
    uint32_t wavesum[4];
};  // ~61 KB -> 2 blocks/CU

__device__ __forceinline__ uint32_t fkey(float x) {
    return __float_as_uint(fabsf(x));  // monotone for non-negative floats
}

__device__ void prepass_hist(SortSmem& sm, const float* __restrict__ rawA)
{
    // pass-0 digit histogram: digit = (fkey>>10)&255 (mantissa bits, ~uniform)
    const int tid = threadIdx.x;
    const float4* r4 = (const float4*)rawA;
#pragma unroll 4
    for (int i = 0; i < ROW_N / 4 / ST; ++i) {   // 16
        float4 f = r4[i * ST + tid];
        atomicAdd(&sm.hist[(fkey(f.x) >> 10) & 255u], 1u);
        atomicAdd(&sm.hist[(fkey(f.y) >> 10) & 255u], 1u);
        atomicAdd(&sm.hist[(fkey(f.z) >> 10) & 255u], 1u);
        atomicAdd(&sm.hist[(fkey(f.w) >> 10) & 255u], 1u);
    }
    __syncthreads();
}

// One stable radix pass. Key = bits [31:10] of |x| (22 bits, bit31 always 0).
// Digit plan: P0 bits 10-17 (8b), P1 bits 18-24 (7b), P2 bits 25-31 (7b).
// ALL buffers u32. src element after P0: fkey[31:18]<<18 | sneg<<17 | cneg<<16 | idx16.
// tgt element: full |x| bits throughout.
// Rank:
//  P0/P1 (digit ~uniform): ds_atomic_add_rtn on wave-private digit counter.
//  P2 (digit = exponent bits, 3-4 distinct values -> same-address atomics
//      serialize 16-32x): ballot peer-group rank; only the group leader does
//      one atomic; base broadcast via shfl (off critical path until b2).
// Position map: pos = c*8192 + wave*512 + k*64 + lane — wave owns a contiguous
// segment; (program-order k) x (lane-order retirement) = position order within
// the sub [validated R12/R13: absmax unchanged]; wave index is position-monotone.
template <bool IS_SRC, int P>
__device__ void run_pass(SortSmem& sm, const float* __restrict__ rawA,
                         const float* __restrict__ rawS,
                         const uint32_t* __restrict__ inBuf,
                         uint32_t* __restrict__ outBuf)
{
    constexpr int DBITS = (P == 0) ? 8 : 7;
    constexpr int ND = 1 << DBITS;
    constexpr int DSH = (P == 0) ? 10 : (P == 1 ? 18 : 25);  // digit shift in staged val
    constexpr bool P0SRC = IS_SRC && (P == 0);

    const int tid = threadIdx.x;
    const int lane = tid & 63;
    const int wave = tid >> 6;
    const uint64_t lane_lt = (1ull << lane) - 1ull;

    // ---- pass start: sbase[0] = exclusive scan of hist; zero hist for reuse ----
    {
        uint32_t h = 0u, incl = 0u;
        if (tid < ND) {
            h = sm.hist[tid];
            sm.hist[tid] = 0u;
            incl = h;
#pragma unroll
            for (int dd = 1; dd < 64; dd <<= 1) {
                uint32_t t = __shfl_up(incl, dd, 64);
                if (lane >= dd) incl += t;
            }
            if (lane == 63) sm.wavesum[tid >> 6] = incl;
        }
        __syncthreads();
        if (tid < ND) {
            uint32_t woff = 0u;
#pragma unroll
            for (int j = 0; j < ND / 64; ++j)
                if (j < (tid >> 6)) woff += sm.wavesum[j];
            sm.sbase[0][tid] = woff + incl - h;
        }
        __syncthreads();
    }

    // returns {value, digit}; pos = c*CHUNK + wave*512 + k*64 + lane
    auto loadE = [&](int c, int k) -> uint2 {
        const int pos = c * CHUNK + (wave << 9) + (k << 6) + lane;
        if constexpr (P == 0) {
            float av = rawA[pos];
            uint32_t kk = fkey(av);
            if constexpr (IS_SRC) {
                float sv = rawS[pos];
                uint32_t o = ((kk >> 18) << 18) | (uint32_t)pos;
                if (av < 0.f) o |= 1u << 16;
                if (sv < 0.f) o |= 1u << 17;
                return make_uint2(o, (kk >> 10) & 255u);
            } else {
                return make_uint2(kk, (kk >> 10) & 255u);
            }
        } else {
            uint32_t v = inBuf[pos];
            return make_uint2(v, (v >> DSH) & (ND - 1));
        }
    };

    uint2 e[EPT];
#pragma unroll
    for (int k = 0; k < EPT; ++k) e[k] = loadE(0, k);

    for (int c = 0; c < NCHUNK; ++c) {
        const int par = c & 1;

        // ---- zero own whist row (wave-private, program-ordered vs own atomics) ----
        {
            uint4 z = make_uint4(0u, 0u, 0u, 0u);
            uint4* rp = (uint4*)&sm.whist[wave * ND];
            if (lane < ND / 4) rp[lane] = z;
        }

        // ---- rank within sub (k=0..7 in program order) ----
        uint32_t rk[EPT];
        if constexpr (P == 2) {
            // ballot peer-group rank; leader-only atomic (skewed digits)
#pragma unroll
            for (int k = 0; k < EPT; ++k) {
                const uint32_t d = e[k].y;
                uint64_t m = ~0ull;
#pragma unroll
                for (int b = 0; b < DBITS; ++b) {
                    uint64_t bal = __ballot((d >> b) & 1u);
                    m &= ((d >> b) & 1u) ? bal : ~bal;
                }
                const uint32_t rw = (uint32_t)__popcll(m & lane_lt);
                const int leader = (int)(__ffsll((unsigned long long)m) - 1);
                uint32_t base = 0u;
                if (rw == 0u)
                    base = atomicAdd(&sm.whist[(wave << DBITS) + d],
                                     (uint32_t)__popcll(m));
                base = (uint32_t)__shfl((int)base, leader, 64);
                rk[k] = base + rw;
            }
        } else {
#pragma unroll
            for (int k = 0; k < EPT; ++k)
                rk[k] = atomicAdd(&sm.whist[(wave << DBITS) + e[k].y], 1u);
        }

        // ---- fused histogram for next pass ----
        if constexpr (P == 0) {
            // next digit = bits 18-24 (mostly mantissa): plain atomics
#pragma unroll
            for (int k = 0; k < EPT; ++k)
                atomicAdd(&sm.hist[(e[k].x >> 18) & 127u], 1u);
        } else if constexpr (P == 1) {
            // next digit = exponent bits 25-31: skewed -> leader-aggregated
#pragma unroll
            for (int k = 0; k < EPT; ++k) {
                const uint32_t nd = (e[k].x >> 25) & 127u;
                uint64_t m = ~0ull;
#pragma unroll
                for (int b = 0; b < 7; ++b) {
                    uint64_t bal = __ballot((nd >> b) & 1u);
                    m &= ((nd >> b) & 1u) ? bal : ~bal;
                }
                if ((m & lane_lt) == 0ull)
                    atomicAdd(&sm.hist[nd], (uint32_t)__popcll(m));
            }
        }
        __syncthreads();  // b1: whist counts complete

        // ---- scan A: per-digit totals + wave-level inclusive scan ----
        uint32_t tot = 0u, incl = 0u;
        if (tid < ND) {
#pragma unroll
            for (int s = 0; s < SUBS; ++s) tot += sm.whist[(s << DBITS) + tid];
            incl = tot;
#pragma unroll
            for (int dd = 1; dd < 64; dd <<= 1) {
                uint32_t t = __shfl_up(incl, dd, 64);
                if (lane >= dd) incl += t;
            }
            if (lane == 63) sm.wavesum[tid >> 6] = incl;
        }
        __syncthreads();  // b1b

        // ---- scan B: local starts -> whist local prefixes; adj & next sbase ----
        if (tid < ND) {
            uint32_t woff = 0u;
#pragma unroll
            for (int j = 0; j < ND / 64; ++j)
                if (j < (tid >> 6)) woff += sm.wavesum[j];
            const uint32_t ls = woff + incl - tot;
            uint32_t run = ls;
#pragma unroll
            for (int s = 0; s < SUBS; ++s) {
                uint32_t t = sm.whist[(s << DBITS) + tid];
                sm.whist[(s << DBITS) + tid] = run;
                run += t;
            }
            const uint32_t sb = sm.sbase[par][tid];
            sm.adj[par][tid] = sb - ls;
            sm.sbase[par ^ 1][tid] = sb + tot;
        }
        __syncthreads();  // b2: local offsets ready

        // ---- LDS stage scatter (slot = base + rank) + global prefetch ----
#pragma unroll
        for (int k = 0; k < EPT; ++k) {
            const uint32_t s = sm.whist[(wave << DBITS) + e[k].y] + rk[k];
            sm.stage[s] = e[k].x;
            if constexpr (P0SRC) sm.dstg[s] = (uint8_t)e[k].y;
        }
        uint2 n[EPT];
#pragma unroll
        for (int k = 0; k < EPT; ++k) n[k] = make_uint2(0u, 0u);
        if (c + 1 < NCHUNK) {
#pragma unroll
            for (int k = 0; k < EPT; ++k) n[k] = loadE(c + 1, k);
        }
        __syncthreads();  // b3: stage complete

        // ---- coalesced copy-out: slot i -> adj[d] + i ----
#pragma unroll
        for (int h = 0; h < EPT; ++h) {
            const int slot = tid + (h << 10);
            const uint32_t u = sm.stage[slot];
            uint32_t d;
            if constexpr (P0SRC) d = sm.dstg[slot];
            else                 d = (u >> DSH) & (ND - 1);
            const uint32_t go = sm.adj[par][d] + (uint32_t)slot;
            uint32_t ov = u;
            if constexpr (IS_SRC && P == 2) ov = u & 0x3FFFFu;  // idx+signs only
            outBuf[go] = ov;
        }
#pragma unroll
        for (int k = 0; k < EPT; ++k) e[k] = n[k];
    }
    __syncthreads();  // seal pass: writes drained before next pass reads
}

__device__ __forceinline__ float detail_one(float c, float s) {
    const float f = (c < 0.f) ? ((s < 0.f) ? -1.f : COS_04PI)
                              : ((s < 0.f) ? -COS_04PI : 1.f);
    return (0.4f * fabsf(c) + 0.6f * fabsf(s)) * f;
}

} // namespace

__global__ __launch_bounds__(ST, 8)
void sort_kernel(const float* __restrict__ ca, const float* __restrict__ sa,
                 uint32_t* srcA, uint32_t* srcB,
                 uint32_t* tgtA, uint32_t* tgtB, uint32_t* tgtF)
{
    __shared__ SortSmem sm;
    const int row = blockIdx.x >> 1;
    if (threadIdx.x < 256) sm.hist[threadIdx.x] = 0u;
    __syncthreads();

    if ((blockIdx.x & 1) == 0) {
        const float* cRow = ca + (size_t)row * ROW_N;
        const float* sRow = sa + (size_t)row * ROW_N;
        uint32_t* A = srcA + (size_t)row * ROW_N;
        uint32_t* B = srcB + (size_t)row * ROW_N;
        prepass_hist(sm, cRow);
        run_pass<true, 0>(sm, cRow, sRow, nullptr, A);
        run_pass<true, 1>(sm, nullptr, nullptr, A, B);
        run_pass<true, 2>(sm, nullptr, nullptr, B, A);  // final: back into A (srcF)
    } else {
        const float* sRow = sa + (size_t)row * ROW_N;
        uint32_t* A = tgtA + (size_t)row * ROW_N;
        uint32_t* B = tgtB + (size_t)row * ROW_N;
        uint32_t* F = tgtF + (size_t)row * ROW_N;
        prepass_hist(sm, sRow);
        run_pass<false, 0>(sm, sRow, nullptr, nullptr, A);
        run_pass<false, 1>(sm, nullptr, nullptr, A, B);
        run_pass<false, 2>(sm, nullptr, nullptr, B, F);
    }
}

// out0[row, idx] = t_sorted[row, k] * cos(0.8*ph(c) + 0.2*ph(s))
// srcF flat u32 [ROWS][ROW_N]: idx16 | cneg<<16 | sneg<<17 (rank order).
// tgtF flat u32 [ROWS][ROW_N]: exact |style| float bits, sorted.
__global__ __launch_bounds__(256)
void approx_finalize(const uint32_t* __restrict__ srcF,
                     const uint32_t* __restrict__ tgtF,
                     float* __restrict__ out0)
{
    const size_t kk = (size_t)blockIdx.x * blockDim.x + threadIdx.x;
    const uint32_t v = srcF[kk];
    const size_t j = ((kk >> 16) << 16) | (v & 0xFFFFu);
    const float t = __uint_as_float(tgtF[kk]);
    const uint32_t cneg = (v >> 16) & 1u;
    const uint32_t sneg = (v >> 17) & 1u;
    const float f = cneg ? (sneg ? -1.f : -COS_02PI)
                         : (sneg ? COS_02PI : 1.f);
    out0[j] = t * f;
}

__global__ __launch_bounds__(256)
void details_kernel(const f4v* __restrict__ ch, const f4v* __restrict__ sh,
                    const f4v* __restrict__ cv, const f4v* __restrict__ sv,
                    const f4v* __restrict__ cd, const f4v* __restrict__ sd,
                    f4v* __restrict__ oh, f4v* __restrict__ ov,
                    f4v* __restrict__ od)
{
    const size_t i = (size_t)blockIdx.x * blockDim.x + threadIdx.x;
    f4v a, b, r;
    a = ch[i]; b = sh[i];
    r.x = detail_one(a.x, b.x); r.y = detail_one(a.y, b.y);
    r.z = detail_one(a.z, b.z); r.w = detail_one(a.w, b.w);
    oh[i] = r;
    a = cv[i]; b = sv[i];
    r.x = detail_one(a.x, b.x); r.y = detail_one(a.y, b.y);
    r.z = detail_one(a.z, b.z); r.w = detail_one(a.w, b.w);
    ov[i] = r;
    a = cd[i]; b = sd[i];
    r.x = detail_one(a.x, b.x); r.y = detail_one(a.y, b.y);
    r.z = detail_one(a.z, b.z); r.w = detail_one(a.w, b.w);
    od[i] = r;
}

extern "C" void kernel_launch(void* const* d_in, const int* in_sizes, int n_in,
                              void* d_out, int out_size, void* d_ws, size_t ws_size,
                              hipStream_t stream)
{
    (void)in_sizes; (void)n_in; (void)out_size; (void)ws_size;
    const float* ca = (const float*)d_in[0];
    const float* ch = (const float*)d_in[1];
    const float* cv = (const float*)d_in[2];
    const float* cd = (const float*)d_in[3];
    const float* sa = (const float*)d_in[4];
    const float* sh = (const float*)d_in[5];
    const float* sv = (const float*)d_in[6];
    const float* sd = (const float*)d_in[7];

    float* out = (float*)d_out;
    float* out_a = out;
    float* out_h = out + NTOT;
    float* out_v = out + 2 * NTOT;
    float* out_d = out + 3 * NTOT;

    // Buffers (all u32; ws >= 192 MiB used, >=256 MiB proven by R10):
    //  src: P0 raw -> srcA (ws[0,64MiB)); P1 srcA -> srcB (ws[64,128));
    //       P2 srcB -> srcA (= srcF, flat idx+signs in rank order).
    //  tgt: P0 -> out_d slice; P1 -> out_h slice; P2 -> tgtF (ws[128,192)).
    //  finalize reads ONLY ws (srcF + tgtF) -> out_h/v/d free for details.
    //  Keep sort scatter isolated from streaming traffic (R8/R10 lesson).
    uint32_t* srcA = (uint32_t*)d_ws;
    uint32_t* srcB = (uint32_t*)((char*)d_ws + NTOT * 4);
    uint32_t* tgtF = (uint32_t*)((char*)d_ws + NTOT * 8);
    uint32_t* tgtA = (uint32_t*)out_d;
    uint32_t* tgtB = (uint32_t*)out_h;

    sort_kernel<<<2 * ROWS, ST, 0, stream>>>(ca, sa, srcA, srcB, tgtA, tgtB, tgtF);

    approx_finalize<<<(int)(NTOT / 256), 256, 0, stream>>>(srcA, tgtF, out_a);

    details_kernel<<<(int)(NTOT / 4 / 256), 256, 0, stream>>>(
        (const f4v*)ch, (const f4v*)sh,
        (const f4v*)cv, (const f4v*)sv,
        (const f4v*)cd, (const f4v*)sd,
        (f4v*)out_h, (f4v*)out_v, (f4v*)out_d);
}